// Round 1
// baseline (544.107 us; speedup 1.0000x reference)
//
#include <hip/hip_runtime.h>
#include <math.h>

// ---- static config (mirror of reference) ----
#define GNUM 4
#define NG 512
#define NN 2048
#define EE 32768
#define NE (EE + NN)          // 34816 (edges + self loops)
#define HC 128
#define HEADS 4
#define HID 32
#define GRID_PTS 500
#define QN 20
#define ODIM 32

#define LOG2E 1.44269504088896340736f
#define NEG_HALF_LOG2E -0.72134752044448170368f
#define N_POW_M02 0.2871745887492588f   // 512^-0.2

__device__ __forceinline__ float fexp2(float x){ return __builtin_amdgcn_exp2f(x); }

// ---------------- init accumulators ----------------
__global__ void k_init_acc(float* macc, float* kacc){
  int t = threadIdx.x;
  if (t < GNUM*ODIM){ macc[t] = 0.f; kacc[t] = 0.f; }
}

// ---------------- per-(graph,dim) stats ----------------
// block = (g*128+d), 256 threads reduce 512 nodes
__global__ __launch_bounds__(256) void k_stats(const float* __restrict__ cur,
                        float* __restrict__ pmean, float* __restrict__ pmax,
                        float* __restrict__ gmn, float* __restrict__ gstep,
                        float* __restrict__ kcoef){
  int g = blockIdx.x >> 7, d = blockIdx.x & 127;
  int t = threadIdx.x;
  const float* base = cur + (size_t)g*NG*HC + d;
  float v0 = base[(size_t)t*HC];
  float v1 = base[(size_t)(t+256)*HC];
  float mn = fminf(v0,v1), mx = fmaxf(v0,v1);
  float sm = v0+v1, sq = v0*v0+v1*v1;
  __shared__ float4 red[256];
  red[t] = make_float4(mn, mx, sm, sq);
  __syncthreads();
  for (int s=128; s>0; s>>=1){
    if (t < s){
      float4 a = red[t], b = red[t+s];
      red[t] = make_float4(fminf(a.x,b.x), fmaxf(a.y,b.y), a.z+b.z, a.w+b.w);
    }
    __syncthreads();
  }
  if (t==0){
    float4 r = red[0];
    float mean = r.z * (1.f/NG);
    float var  = fmaxf(r.w * (1.f/NG) - mean*mean, 0.f);
    float sd   = sqrtf(var) + (1e-8f/3.f);
    float h    = 1.06f * sd * N_POW_M02;
    float lo = r.x - 1e-6f, hi = r.y + 1e-6f;
    pmean[blockIdx.x] = mean;
    pmax[blockIdx.x]  = r.y;
    gmn[blockIdx.x]   = lo;
    gstep[blockIdx.x] = (hi - lo) * (1.f/(GRID_PTS-1));
    kcoef[blockIdx.x] = NEG_HALF_LOG2E / (h*h);
  }
}

// ---------------- pooled linear head ----------------
// 1 block, 128 threads: (g,o)
__global__ void k_pool_h(const float* __restrict__ pmean, const float* __restrict__ pmax,
                         const float* __restrict__ pool_w,
                         const float* __restrict__ lpW, const float* __restrict__ lpb,
                         float* macc){
  int t = threadIdx.x;
  int g = t >> 5, o = t & 31;
  float pw0 = pool_w[0], pw1 = pool_w[1];
  float acc = lpb[o];
  for (int d=0; d<HC; ++d){
    float wp = pw0*pmean[g*HC+d] + pw1*pmax[g*HC+d];
    acc += wp * lpW[d*ODIM + o];
  }
  macc[t] += acc;
}

// ---------------- KDE density (dominant kernel) ----------------
// block = (g*128+d); 256 threads; thread t handles grid pts t and t+256
__global__ __launch_bounds__(256) void k_density(const float* __restrict__ cur,
                          const float* __restrict__ gmn, const float* __restrict__ gstep,
                          const float* __restrict__ kcoef,
                          float* __restrict__ density){
  int g = blockIdx.x >> 7, d = blockIdx.x & 127;
  int t = threadIdx.x;
  __shared__ __align__(16) float xs[NG];
  const float* base = cur + (size_t)g*NG*HC + d;
  xs[t]     = base[(size_t)t*HC];
  xs[t+256] = base[(size_t)(t+256)*HC];
  __syncthreads();
  float lo = gmn[blockIdx.x], st = gstep[blockIdx.x], k = kcoef[blockIdx.x];
  float gv0 = lo + st*(float)t;
  float gv1 = lo + st*(float)(t+256);
  float acc0 = 0.f, acc1 = 0.f;
  const float4* xs4 = (const float4*)xs;
  #pragma unroll 4
  for (int i=0; i<NG/4; ++i){
    float4 x4 = xs4[i];
    float a,b;
    a = gv0-x4.x; acc0 += fexp2(k*a*a);  b = gv1-x4.x; acc1 += fexp2(k*b*b);
    a = gv0-x4.y; acc0 += fexp2(k*a*a);  b = gv1-x4.y; acc1 += fexp2(k*b*b);
    a = gv0-x4.z; acc0 += fexp2(k*a*a);  b = gv1-x4.z; acc1 += fexp2(k*b*b);
    a = gv0-x4.w; acc0 += fexp2(k*a*a);  b = gv1-x4.w; acc1 += fexp2(k*b*b);
  }
  float* drow = density + (size_t)blockIdx.x * GRID_PTS;
  if (t < GRID_PTS)       drow[t]     = acc0;
  if (t+256 < GRID_PTS)   drow[t+256] = acc1;
}

// ---------------- cdf scan + soft quantiles ----------------
// block = (g*128+d); 512 threads
__global__ __launch_bounds__(512) void k_cdf_quant(const float* __restrict__ density,
                        const float* __restrict__ gmn, const float* __restrict__ gstep,
                        float* __restrict__ qv){
  int gd = blockIdx.x;
  int t = threadIdx.x;
  __shared__ float sdm[512];
  __shared__ float redA[8], redB[8];
  sdm[t] = (t < GRID_PTS) ? density[(size_t)gd*GRID_PTS + t] : 0.f;
  __syncthreads();
  // Hillis-Steele inclusive scan over 512
  for (int off=1; off<512; off<<=1){
    float v = sdm[t];
    float add = (t >= off) ? sdm[t-off] : 0.f;
    __syncthreads();
    sdm[t] = v + add;
    __syncthreads();
  }
  float total = sdm[GRID_PTS-1];
  float invt = 1.f / fmaxf(total, 1e-8f);
  float c = (t < GRID_PTS) ? sdm[t]*invt : 0.f;
  float gvv = gmn[gd] + gstep[gd]*(float)t;
  int g = gd >> 7, d = gd & 127;
  float* qout = qv + (size_t)g*(HC*QN) + (size_t)d*QN;
  int wave = t >> 6, lane = t & 63;
  for (int q=0; q<QN; ++q){
    float Qq = (float)q * (1.f/(QN-1));
    float w = 0.f;
    if (t < GRID_PTS){
      float dist = fabsf(c - Qq);
      float e = fexp2(144.2695040889f * dist);   // exp(100*dist)
      w = 1.f / (1.f + e);                       // sigmoid(-100*dist)
    }
    float gw = gvv * w;
    for (int s=32; s>0; s>>=1){
      w  += __shfl_down(w,  s, 64);
      gw += __shfl_down(gw, s, 64);
    }
    if (lane==0){ redA[wave] = w; redB[wave] = gw; }
    __syncthreads();
    if (t==0){
      float sw=0.f, sgw=0.f;
      #pragma unroll
      for (int i=0;i<8;++i){ sw+=redA[i]; sgw+=redB[i]; }
      qout[q] = sgw / (sw + 1e-8f);
    }
    __syncthreads();
  }
}

// ---------------- KDE projection ----------------
// 1 block, 128 threads: (g,o), dot over 2560
__global__ void k_kde_proj(const float* __restrict__ qv, const float* __restrict__ kW,
                           const float* __restrict__ kb, float* kacc){
  int t = threadIdx.x;
  int g = t >> 5, o = t & 31;
  float acc = kb[o];
  const float* qg = qv + (size_t)g*(HC*QN);
  for (int i=0; i<HC*QN; ++i)
    acc += qg[i] * kW[(size_t)i*ODIM + o];
  kacc[t] += acc;
}

// ---------------- GAT: x @ W ----------------
// block: 256 threads cover 2 rows x 128 cols; grid 1024
__global__ __launch_bounds__(256) void k_xw(const float* __restrict__ cur,
                     const float* __restrict__ W, float* __restrict__ xh){
  int t = threadIdx.x;
  int ln = t >> 7, j = t & 127;
  int n = blockIdx.x*2 + ln;
  __shared__ float rows[2][HC];
  rows[ln][j] = cur[(size_t)n*HC + j];
  __syncthreads();
  float acc = 0.f;
  #pragma unroll 8
  for (int c=0; c<HC; ++c)
    acc += rows[ln][c] * W[(size_t)c*HC + j];
  xh[(size_t)n*HC + j] = acc;
}

// ---------------- attention logits ----------------
__global__ void k_al(const float* __restrict__ xh, const float* __restrict__ as_,
                     const float* __restrict__ ad_, float* __restrict__ als,
                     float* __restrict__ ald){
  int idx = blockIdx.x*blockDim.x + threadIdx.x;
  if (idx >= NN*HEADS) return;
  int n = idx >> 2, h = idx & 3;
  const float* xr = xh + (size_t)n*HC + h*HID;
  float s = 0.f, dd = 0.f;
  #pragma unroll
  for (int c=0;c<HID;++c){ s += xr[c]*as_[h*HID+c]; dd += xr[c]*ad_[h*HID+c]; }
  als[idx] = s; ald[idx] = dd;
}

// ---------------- GAT init: out=bias, emax=-inf, denom=0 ----------------
__global__ void k_gat_init(const float* __restrict__ bias, float* __restrict__ out,
                           float* __restrict__ emax, float* __restrict__ denom){
  int idx = blockIdx.x*blockDim.x + threadIdx.x;
  if (idx < NN*HC) out[idx] = bias[idx & 127];
  if (idx < NN*HEADS){ emax[idx] = -INFINITY; denom[idx] = 0.f; }
}

__device__ __forceinline__ void atomicMaxF(float* a, float v){
  if (v >= 0.f) atomicMax((int*)a, __float_as_int(v));
  else          atomicMin((unsigned int*)a, __float_as_uint(v));
}

__global__ void k_emax(const int* __restrict__ src, const int* __restrict__ dst,
                       const float* __restrict__ als, const float* __restrict__ ald,
                       float* __restrict__ emax){
  int eid = blockIdx.x*blockDim.x + threadIdx.x;
  if (eid >= NE) return;
  int s = (eid < EE) ? src[eid] : (eid - EE);
  int d = (eid < EE) ? dst[eid] : (eid - EE);
  #pragma unroll
  for (int h=0; h<HEADS; ++h){
    float e = als[s*4+h] + ald[d*4+h];
    e = (e >= 0.f) ? e : 0.2f*e;
    atomicMaxF(&emax[d*4+h], e);
  }
}

__global__ void k_eexp(const int* __restrict__ src, const int* __restrict__ dst,
                       const float* __restrict__ als, const float* __restrict__ ald,
                       const float* __restrict__ emax, float* __restrict__ eexp,
                       float* __restrict__ denom){
  int eid = blockIdx.x*blockDim.x + threadIdx.x;
  if (eid >= NE) return;
  int s = (eid < EE) ? src[eid] : (eid - EE);
  int d = (eid < EE) ? dst[eid] : (eid - EE);
  #pragma unroll
  for (int h=0; h<HEADS; ++h){
    float e = als[s*4+h] + ald[d*4+h];
    e = (e >= 0.f) ? e : 0.2f*e;
    float v = fexp2(LOG2E*(e - emax[d*4+h]));
    eexp[eid*4+h] = v;
    atomicAdd(&denom[d*4+h], v);
  }
}

// per (edge, channel) atomic aggregation
__global__ void k_agg(const int* __restrict__ src, const int* __restrict__ dst,
                      const float* __restrict__ eexp, const float* __restrict__ denom,
                      const float* __restrict__ xh, float* __restrict__ out){
  long long gid = (long long)blockIdx.x*blockDim.x + threadIdx.x;
  if (gid >= (long long)NE*HC) return;
  int eid = (int)(gid >> 7);
  int c   = (int)(gid & 127);
  int h   = c >> 5;
  int s = (eid < EE) ? src[eid] : (eid - EE);
  int d = (eid < EE) ? dst[eid] : (eid - EE);
  float alpha = eexp[eid*4+h] / (denom[d*4+h] + 1e-16f);
  atomicAdd(&out[(size_t)d*HC + c], alpha * xh[(size_t)s*HC + c]);
}

__global__ void k_relu(float* __restrict__ out){
  int idx = blockIdx.x*blockDim.x + threadIdx.x;
  if (idx < NN*HC) out[idx] = fmaxf(out[idx], 0.f);
}

// ---------------- final risk ----------------
__global__ void k_final(const float* __restrict__ macc, const float* __restrict__ kacc,
                        const float* __restrict__ beta, const float* __restrict__ h0,
                        float* __restrict__ out){
  int t = threadIdx.x;   // 128
  int g = t >> 5, o = t & 31;
  __shared__ float sdm[128];
  sdm[t] = (macc[t] + kacc[t]) * (1.f/3.f) * beta[o];
  __syncthreads();
  if ((t & 31) == 0){
    float s = 0.f;
    #pragma unroll
    for (int i=0;i<32;++i) s += sdm[g*32+i];
    out[g] = s + h0[0];
  }
}

extern "C" void kernel_launch(void* const* d_in, const int* in_sizes, int n_in,
                              void* d_out, int out_size, void* d_ws, size_t ws_size,
                              hipStream_t stream) {
  (void)in_sizes; (void)n_in; (void)out_size; (void)ws_size;
  const float* x    = (const float*)d_in[0];
  const int*   ei   = (const int*)d_in[1];
  const int*   srcp = ei;
  const int*   dstp = ei + EE;
  const float* W[2]   = {(const float*)d_in[3], (const float*)d_in[7]};
  const float* As[2]  = {(const float*)d_in[4], (const float*)d_in[8]};
  const float* Ad[2]  = {(const float*)d_in[5], (const float*)d_in[9]};
  const float* Bi[2]  = {(const float*)d_in[6], (const float*)d_in[10]};
  const float* lpW[3] = {(const float*)d_in[11], (const float*)d_in[13], (const float*)d_in[15]};
  const float* lpb[3] = {(const float*)d_in[12], (const float*)d_in[14], (const float*)d_in[16]};
  const float* kW[3]  = {(const float*)d_in[17], (const float*)d_in[19], (const float*)d_in[21]};
  const float* kb[3]  = {(const float*)d_in[18], (const float*)d_in[20], (const float*)d_in[22]};
  const float* poolw  = (const float*)d_in[23];
  const float* beta   = (const float*)d_in[24];
  const float* h0     = (const float*)d_in[25];
  float* out = (float*)d_out;

  // workspace layout (floats)
  float* ws = (float*)d_ws;
  float* cur1   = ws;                 // 262144
  float* cur2   = cur1 + 262144;      // 262144
  float* xh     = cur2 + 262144;      // 262144
  float* als    = xh + 262144;        // 8192
  float* ald    = als + 8192;         // 8192
  float* emax   = ald + 8192;         // 8192
  float* denom  = emax + 8192;        // 8192
  float* eexp   = denom + 8192;       // 139264
  float* pmean  = eexp + 139264;      // 512
  float* pmax   = pmean + 512;        // 512
  float* gmn    = pmax + 512;         // 512
  float* gstep  = gmn + 512;          // 512
  float* kcoef  = gstep + 512;        // 512
  float* density= kcoef + 512;        // 256000
  float* qv     = density + 256000;   // 10240
  float* macc   = qv + 10240;         // 128
  float* kacc   = macc + 128;         // 128

  auto readout = [&](const float* cur, int i){
    k_stats    <<<512, 256, 0, stream>>>(cur, pmean, pmax, gmn, gstep, kcoef);
    k_pool_h   <<<1,   128, 0, stream>>>(pmean, pmax, poolw, lpW[i], lpb[i], macc);
    k_density  <<<512, 256, 0, stream>>>(cur, gmn, gstep, kcoef, density);
    k_cdf_quant<<<512, 512, 0, stream>>>(density, gmn, gstep, qv);
    k_kde_proj <<<1,   128, 0, stream>>>(qv, kW[i], kb[i], kacc);
  };
  auto gat = [&](const float* in, float* o, int l, bool relu){
    k_xw      <<<1024, 256, 0, stream>>>(in, W[l], xh);
    k_al      <<<32,   256, 0, stream>>>(xh, As[l], Ad[l], als, ald);
    k_gat_init<<<1024, 256, 0, stream>>>(Bi[l], o, emax, denom);
    k_emax    <<<(NE+255)/256, 256, 0, stream>>>(srcp, dstp, als, ald, emax);
    k_eexp    <<<(NE+255)/256, 256, 0, stream>>>(srcp, dstp, als, ald, emax, eexp, denom);
    k_agg     <<<(int)(((long long)NE*HC+255)/256), 256, 0, stream>>>(srcp, dstp, eexp, denom, xh, o);
    if (relu) k_relu<<<1024, 256, 0, stream>>>(o);
  };

  k_init_acc<<<1, 128, 0, stream>>>(macc, kacc);
  readout(x, 0);
  gat(x, cur1, 0, true);
  readout(cur1, 1);
  gat(cur1, cur2, 1, false);
  readout(cur2, 2);
  k_final<<<1, 128, 0, stream>>>(macc, kacc, beta, h0, out);
}

// Round 2
// 380.666 us; speedup vs baseline: 1.4294x; 1.4294x over previous
//
#include <hip/hip_runtime.h>
#include <math.h>

// ---- static config (mirror of reference) ----
#define GNUM 4
#define NG 512
#define NN 2048
#define EE 32768
#define NE (EE + NN)          // 34816 (edges + self loops)
#define HC 128
#define HEADS 4
#define HID 32
#define GRID_PTS 500
#define QN 20
#define ODIM 32
#define KCHUNKS 20            // 2560 rows / 128 per chunk

#define LOG2E 1.44269504088896340736f
#define NEG_HALF_LOG2E -0.72134752044448170368f
#define N_POW_M02 0.2871745887492588f   // 512^-0.2

__device__ __forceinline__ float fexp2(float x){ return __builtin_amdgcn_exp2f(x); }

// ---------------- init accumulators ----------------
__global__ void k_init_acc(float* macc, float* kacc){
  int t = threadIdx.x;
  if (t < GNUM*ODIM){ macc[t] = 0.f; kacc[t] = 0.f; }
}

// ---------------- per-(graph,dim) stats ----------------
// block = (g*128+d), 256 threads reduce 512 nodes
__global__ __launch_bounds__(256) void k_stats(const float* __restrict__ cur,
                        float* __restrict__ pmean, float* __restrict__ pmax,
                        float* __restrict__ gmn, float* __restrict__ gstep,
                        float* __restrict__ kcoef){
  int g = blockIdx.x >> 7, d = blockIdx.x & 127;
  int t = threadIdx.x;
  const float* base = cur + (size_t)g*NG*HC + d;
  float v0 = base[(size_t)t*HC];
  float v1 = base[(size_t)(t+256)*HC];
  float mn = fminf(v0,v1), mx = fmaxf(v0,v1);
  float sm = v0+v1, sq = v0*v0+v1*v1;
  __shared__ float4 red[256];
  red[t] = make_float4(mn, mx, sm, sq);
  __syncthreads();
  for (int s=128; s>0; s>>=1){
    if (t < s){
      float4 a = red[t], b = red[t+s];
      red[t] = make_float4(fminf(a.x,b.x), fmaxf(a.y,b.y), a.z+b.z, a.w+b.w);
    }
    __syncthreads();
  }
  if (t==0){
    float4 r = red[0];
    float mean = r.z * (1.f/NG);
    float var  = fmaxf(r.w * (1.f/NG) - mean*mean, 0.f);
    float sd   = sqrtf(var) + (1e-8f/3.f);
    float h    = 1.06f * sd * N_POW_M02;
    float lo = r.x - 1e-6f, hi = r.y + 1e-6f;
    pmean[blockIdx.x] = mean;
    pmax[blockIdx.x]  = r.y;
    gmn[blockIdx.x]   = lo;
    gstep[blockIdx.x] = (hi - lo) * (1.f/(GRID_PTS-1));
    kcoef[blockIdx.x] = NEG_HALF_LOG2E / (h*h);
  }
}

// ---------------- pooled linear head ----------------
// grid = GNUM, 128 threads: o = t&31, d-group = t>>5 (4 groups)
__global__ void k_pool_h(const float* __restrict__ pmean, const float* __restrict__ pmax,
                         const float* __restrict__ pool_w,
                         const float* __restrict__ lpW, const float* __restrict__ lpb,
                         float* macc){
  int g = blockIdx.x;
  int t = threadIdx.x;
  int o = t & 31, dg = t >> 5;
  float pw0 = pool_w[0], pw1 = pool_w[1];
  float acc = 0.f;
  for (int d = dg; d < HC; d += 4){
    float wp = pw0*pmean[g*HC+d] + pw1*pmax[g*HC+d];
    acc += wp * lpW[d*ODIM + o];
  }
  __shared__ float red[128];
  red[t] = acc;
  __syncthreads();
  if (dg < 2) red[t] += red[t+64];
  __syncthreads();
  if (dg == 0)
    macc[g*ODIM + o] += red[t] + red[t+32] + lpb[o];
}

// ---------------- KDE density (dominant kernel) ----------------
// block = (g*128+d); 256 threads; thread t handles grid pts t and t+256
__global__ __launch_bounds__(256) void k_density(const float* __restrict__ cur,
                          const float* __restrict__ gmn, const float* __restrict__ gstep,
                          const float* __restrict__ kcoef,
                          float* __restrict__ density){
  int g = blockIdx.x >> 7, d = blockIdx.x & 127;
  int t = threadIdx.x;
  __shared__ __align__(16) float xs[NG];
  const float* base = cur + (size_t)g*NG*HC + d;
  xs[t]     = base[(size_t)t*HC];
  xs[t+256] = base[(size_t)(t+256)*HC];
  __syncthreads();
  float lo = gmn[blockIdx.x], st = gstep[blockIdx.x], k = kcoef[blockIdx.x];
  float gv0 = lo + st*(float)t;
  float gv1 = lo + st*(float)(t+256);
  float acc0 = 0.f, acc1 = 0.f;
  const float4* xs4 = (const float4*)xs;
  #pragma unroll 4
  for (int i=0; i<NG/4; ++i){
    float4 x4 = xs4[i];
    float a,b;
    a = gv0-x4.x; acc0 += fexp2(k*a*a);  b = gv1-x4.x; acc1 += fexp2(k*b*b);
    a = gv0-x4.y; acc0 += fexp2(k*a*a);  b = gv1-x4.y; acc1 += fexp2(k*b*b);
    a = gv0-x4.z; acc0 += fexp2(k*a*a);  b = gv1-x4.z; acc1 += fexp2(k*b*b);
    a = gv0-x4.w; acc0 += fexp2(k*a*a);  b = gv1-x4.w; acc1 += fexp2(k*b*b);
  }
  float* drow = density + (size_t)blockIdx.x * GRID_PTS;
  if (t < GRID_PTS)       drow[t]     = acc0;
  if (t+256 < GRID_PTS)   drow[t+256] = acc1;
}

// ---------------- cdf scan + soft quantiles ----------------
// block = (g*128+d); 512 threads
__global__ __launch_bounds__(512) void k_cdf_quant(const float* __restrict__ density,
                        const float* __restrict__ gmn, const float* __restrict__ gstep,
                        float* __restrict__ qv){
  int gd = blockIdx.x;
  int t = threadIdx.x;
  __shared__ float sdm[512];
  __shared__ float redA[8], redB[8];
  sdm[t] = (t < GRID_PTS) ? density[(size_t)gd*GRID_PTS + t] : 0.f;
  __syncthreads();
  // Hillis-Steele inclusive scan over 512
  for (int off=1; off<512; off<<=1){
    float v = sdm[t];
    float add = (t >= off) ? sdm[t-off] : 0.f;
    __syncthreads();
    sdm[t] = v + add;
    __syncthreads();
  }
  float total = sdm[GRID_PTS-1];
  float invt = 1.f / fmaxf(total, 1e-8f);
  float c = (t < GRID_PTS) ? sdm[t]*invt : 0.f;
  float gvv = gmn[gd] + gstep[gd]*(float)t;
  int g = gd >> 7, d = gd & 127;
  float* qout = qv + (size_t)g*(HC*QN) + (size_t)d*QN;
  int wave = t >> 6, lane = t & 63;
  for (int q=0; q<QN; ++q){
    float Qq = (float)q * (1.f/(QN-1));
    float w = 0.f;
    if (t < GRID_PTS){
      float dist = fabsf(c - Qq);
      float e = fexp2(144.2695040889f * dist);   // exp(100*dist)
      w = 1.f / (1.f + e);                       // sigmoid(-100*dist)
    }
    float gw = gvv * w;
    for (int s=32; s>0; s>>=1){
      w  += __shfl_down(w,  s, 64);
      gw += __shfl_down(gw, s, 64);
    }
    if (lane==0){ redA[wave] = w; redB[wave] = gw; }
    __syncthreads();
    if (t==0){
      float sw=0.f, sgw=0.f;
      #pragma unroll
      for (int i=0;i<8;++i){ sw+=redA[i]; sgw+=redB[i]; }
      qout[q] = sgw / (sw + 1e-8f);
    }
    __syncthreads();
  }
}

// ---------------- KDE projection ----------------
// grid = GNUM*KCHUNKS blocks, 256 threads; o = t&31 (coalesced over kW rows)
__global__ __launch_bounds__(256) void k_kde_proj(const float* __restrict__ qv,
                           const float* __restrict__ kW,
                           const float* __restrict__ kb, float* kacc){
  int g = blockIdx.x / KCHUNKS;
  int chunk = blockIdx.x % KCHUNKS;
  int t = threadIdx.x;
  int o = t & 31, rg = t >> 5;          // 8 row-groups
  const float* qg = qv + (size_t)g*(HC*QN);
  int base = chunk * 128;
  float acc = 0.f;
  #pragma unroll 4
  for (int r = rg; r < 128; r += 8){
    int i = base + r;
    acc += qg[i] * kW[(size_t)i*ODIM + o];
  }
  __shared__ float red[256];
  red[t] = acc;
  __syncthreads();
  if (rg < 4) red[t] += red[t+128];
  __syncthreads();
  if (rg < 2) red[t] += red[t+64];
  __syncthreads();
  if (rg == 0){
    float v = red[t] + red[t+32];
    if (chunk == 0) v += kb[o];
    atomicAdd(&kacc[g*ODIM + o], v);
  }
}

// ---------------- GAT: x @ W ----------------
// block: 256 threads cover 2 rows x 128 cols; grid 1024
__global__ __launch_bounds__(256) void k_xw(const float* __restrict__ cur,
                     const float* __restrict__ W, float* __restrict__ xh){
  int t = threadIdx.x;
  int ln = t >> 7, j = t & 127;
  int n = blockIdx.x*2 + ln;
  __shared__ float rows[2][HC];
  rows[ln][j] = cur[(size_t)n*HC + j];
  __syncthreads();
  float acc = 0.f;
  #pragma unroll 8
  for (int c=0; c<HC; ++c)
    acc += rows[ln][c] * W[(size_t)c*HC + j];
  xh[(size_t)n*HC + j] = acc;
}

// ---------------- attention logits ----------------
__global__ void k_al(const float* __restrict__ xh, const float* __restrict__ as_,
                     const float* __restrict__ ad_, float* __restrict__ als,
                     float* __restrict__ ald){
  int idx = blockIdx.x*blockDim.x + threadIdx.x;
  if (idx >= NN*HEADS) return;
  int n = idx >> 2, h = idx & 3;
  const float* xr = xh + (size_t)n*HC + h*HID;
  float s = 0.f, dd = 0.f;
  #pragma unroll
  for (int c=0;c<HID;++c){ s += xr[c]*as_[h*HID+c]; dd += xr[c]*ad_[h*HID+c]; }
  als[idx] = s; ald[idx] = dd;
}

// ---------------- GAT init: out=bias, emax=-inf, denom=0 ----------------
__global__ void k_gat_init(const float* __restrict__ bias, float* __restrict__ out,
                           float* __restrict__ emax, float* __restrict__ denom){
  int idx = blockIdx.x*blockDim.x + threadIdx.x;
  if (idx < NN*HC) out[idx] = bias[idx & 127];
  if (idx < NN*HEADS){ emax[idx] = -INFINITY; denom[idx] = 0.f; }
}

__device__ __forceinline__ void atomicMaxF(float* a, float v){
  if (v >= 0.f) atomicMax((int*)a, __float_as_int(v));
  else          atomicMin((unsigned int*)a, __float_as_uint(v));
}

__global__ void k_emax(const int* __restrict__ src, const int* __restrict__ dst,
                       const float* __restrict__ als, const float* __restrict__ ald,
                       float* __restrict__ emax){
  int eid = blockIdx.x*blockDim.x + threadIdx.x;
  if (eid >= NE) return;
  int s = (eid < EE) ? src[eid] : (eid - EE);
  int d = (eid < EE) ? dst[eid] : (eid - EE);
  #pragma unroll
  for (int h=0; h<HEADS; ++h){
    float e = als[s*4+h] + ald[d*4+h];
    e = (e >= 0.f) ? e : 0.2f*e;
    atomicMaxF(&emax[d*4+h], e);
  }
}

__global__ void k_eexp(const int* __restrict__ src, const int* __restrict__ dst,
                       const float* __restrict__ als, const float* __restrict__ ald,
                       const float* __restrict__ emax, float* __restrict__ eexp,
                       float* __restrict__ denom){
  int eid = blockIdx.x*blockDim.x + threadIdx.x;
  if (eid >= NE) return;
  int s = (eid < EE) ? src[eid] : (eid - EE);
  int d = (eid < EE) ? dst[eid] : (eid - EE);
  #pragma unroll
  for (int h=0; h<HEADS; ++h){
    float e = als[s*4+h] + ald[d*4+h];
    e = (e >= 0.f) ? e : 0.2f*e;
    float v = fexp2(LOG2E*(e - emax[d*4+h]));
    eexp[eid*4+h] = v;
    atomicAdd(&denom[d*4+h], v);
  }
}

// per (edge, channel) atomic aggregation
__global__ void k_agg(const int* __restrict__ src, const int* __restrict__ dst,
                      const float* __restrict__ eexp, const float* __restrict__ denom,
                      const float* __restrict__ xh, float* __restrict__ out){
  long long gid = (long long)blockIdx.x*blockDim.x + threadIdx.x;
  if (gid >= (long long)NE*HC) return;
  int eid = (int)(gid >> 7);
  int c   = (int)(gid & 127);
  int h   = c >> 5;
  int s = (eid < EE) ? src[eid] : (eid - EE);
  int d = (eid < EE) ? dst[eid] : (eid - EE);
  float alpha = eexp[eid*4+h] / (denom[d*4+h] + 1e-16f);
  atomicAdd(&out[(size_t)d*HC + c], alpha * xh[(size_t)s*HC + c]);
}

__global__ void k_relu(float* __restrict__ out){
  int idx = blockIdx.x*blockDim.x + threadIdx.x;
  if (idx < NN*HC) out[idx] = fmaxf(out[idx], 0.f);
}

// ---------------- final risk ----------------
__global__ void k_final(const float* __restrict__ macc, const float* __restrict__ kacc,
                        const float* __restrict__ beta, const float* __restrict__ h0,
                        float* __restrict__ out){
  int t = threadIdx.x;   // 128
  int g = t >> 5, o = t & 31;
  __shared__ float sdm[128];
  sdm[t] = (macc[t] + kacc[t]) * (1.f/3.f) * beta[o];
  __syncthreads();
  if ((t & 31) == 0){
    float s = 0.f;
    #pragma unroll
    for (int i=0;i<32;++i) s += sdm[g*32+i];
    out[g] = s + h0[0];
  }
}

extern "C" void kernel_launch(void* const* d_in, const int* in_sizes, int n_in,
                              void* d_out, int out_size, void* d_ws, size_t ws_size,
                              hipStream_t stream) {
  (void)in_sizes; (void)n_in; (void)out_size; (void)ws_size;
  const float* x    = (const float*)d_in[0];
  const int*   ei   = (const int*)d_in[1];
  const int*   srcp = ei;
  const int*   dstp = ei + EE;
  const float* W[2]   = {(const float*)d_in[3], (const float*)d_in[7]};
  const float* As[2]  = {(const float*)d_in[4], (const float*)d_in[8]};
  const float* Ad[2]  = {(const float*)d_in[5], (const float*)d_in[9]};
  const float* Bi[2]  = {(const float*)d_in[6], (const float*)d_in[10]};
  const float* lpW[3] = {(const float*)d_in[11], (const float*)d_in[13], (const float*)d_in[15]};
  const float* lpb[3] = {(const float*)d_in[12], (const float*)d_in[14], (const float*)d_in[16]};
  const float* kW[3]  = {(const float*)d_in[17], (const float*)d_in[19], (const float*)d_in[21]};
  const float* kb[3]  = {(const float*)d_in[18], (const float*)d_in[20], (const float*)d_in[22]};
  const float* poolw  = (const float*)d_in[23];
  const float* beta   = (const float*)d_in[24];
  const float* h0     = (const float*)d_in[25];
  float* out = (float*)d_out;

  // workspace layout (floats)
  float* ws = (float*)d_ws;
  float* cur1   = ws;                 // 262144
  float* cur2   = cur1 + 262144;      // 262144
  float* xh     = cur2 + 262144;      // 262144
  float* als    = xh + 262144;        // 8192
  float* ald    = als + 8192;         // 8192
  float* emax   = ald + 8192;         // 8192
  float* denom  = emax + 8192;        // 8192
  float* eexp   = denom + 8192;       // 139264
  float* pmean  = eexp + 139264;      // 512
  float* pmax   = pmean + 512;        // 512
  float* gmn    = pmax + 512;         // 512
  float* gstep  = gmn + 512;          // 512
  float* kcoef  = gstep + 512;        // 512
  float* density= kcoef + 512;        // 256000
  float* qv     = density + 256000;   // 10240
  float* macc   = qv + 10240;         // 128
  float* kacc   = macc + 128;         // 128

  auto readout = [&](const float* cur, int i){
    k_stats    <<<512, 256, 0, stream>>>(cur, pmean, pmax, gmn, gstep, kcoef);
    k_pool_h   <<<GNUM, 128, 0, stream>>>(pmean, pmax, poolw, lpW[i], lpb[i], macc);
    k_density  <<<512, 256, 0, stream>>>(cur, gmn, gstep, kcoef, density);
    k_cdf_quant<<<512, 512, 0, stream>>>(density, gmn, gstep, qv);
    k_kde_proj <<<GNUM*KCHUNKS, 256, 0, stream>>>(qv, kW[i], kb[i], kacc);
  };
  auto gat = [&](const float* in, float* o, int l, bool relu){
    k_xw      <<<1024, 256, 0, stream>>>(in, W[l], xh);
    k_al      <<<32,   256, 0, stream>>>(xh, As[l], Ad[l], als, ald);
    k_gat_init<<<1024, 256, 0, stream>>>(Bi[l], o, emax, denom);
    k_emax    <<<(NE+255)/256, 256, 0, stream>>>(srcp, dstp, als, ald, emax);
    k_eexp    <<<(NE+255)/256, 256, 0, stream>>>(srcp, dstp, als, ald, emax, eexp, denom);
    k_agg     <<<(int)(((long long)NE*HC+255)/256), 256, 0, stream>>>(srcp, dstp, eexp, denom, xh, o);
    if (relu) k_relu<<<1024, 256, 0, stream>>>(o);
  };

  k_init_acc<<<1, 128, 0, stream>>>(macc, kacc);
  readout(x, 0);
  gat(x, cur1, 0, true);
  readout(cur1, 1);
  gat(cur1, cur2, 1, false);
  readout(cur2, 2);
  k_final<<<1, 128, 0, stream>>>(macc, kacc, beta, h0, out);
}

// Round 3
// 322.987 us; speedup vs baseline: 1.6846x; 1.1786x over previous
//
#include <hip/hip_runtime.h>
#include <math.h>

// ---- static config (mirror of reference) ----
#define GNUM 4
#define NG 512
#define NN 2048
#define EE 32768
#define NE (EE + NN)          // 34816 (edges + self loops)
#define HC 128
#define HEADS 4
#define HID 32
#define GRID_PTS 500
#define QN 20
#define ODIM 32

#define LOG2E 1.44269504088896340736f
#define NEG_HALF_LOG2E -0.72134752044448170368f
#define N_POW_M02 0.2871745887492588f   // 512^-0.2
#define SIG_K 144.269504089f            // 100 * log2(e)

__device__ __forceinline__ float fexp2(float x){ return __builtin_amdgcn_exp2f(x); }
__device__ __forceinline__ float frcp(float x){ return __builtin_amdgcn_rcpf(x); }

// ---------------- zero kacc slots ----------------
__global__ void k_init_acc(float* kacc){
  int t = threadIdx.x;
  if (t < 3*GNUM*ODIM) kacc[t] = 0.f;
}

// ============ fused KDE readout: stats + density + cdf + quantiles + projection ============
// block = (g*128+d), 512 threads (one grid point each; 500 active for density)
__global__ __launch_bounds__(512) void k_kde(const float* __restrict__ cur, int do_relu,
        const float* __restrict__ kW, const float* __restrict__ kb,
        float* __restrict__ kacc, float* __restrict__ pmean, float* __restrict__ pmax_){
  int g = blockIdx.x >> 7, d = blockIdx.x & 127;
  int t = threadIdx.x;
  int lane = t & 63, wave = t >> 6;
  __shared__ __align__(16) float xs[NG];
  __shared__ float4 wred4[8];
  __shared__ float sc[4];
  __shared__ float wsum[8], woff[9];
  __shared__ float redw[QN][8], redg[QN][8];
  __shared__ float qs[QN];

  float v = cur[((size_t)g*NG + t)*HC + d];
  if (do_relu) v = fmaxf(v, 0.f);
  xs[t] = v;
  // wave-level min/max/sum/sumsq
  float mn=v, mx=v, sm=v, sq=v*v;
  #pragma unroll
  for (int m=32; m>0; m>>=1){
    mn = fminf(mn, __shfl_xor(mn, m, 64));
    mx = fmaxf(mx, __shfl_xor(mx, m, 64));
    sm += __shfl_xor(sm, m, 64);
    sq += __shfl_xor(sq, m, 64);
  }
  if (lane==0) wred4[wave] = make_float4(mn,mx,sm,sq);
  __syncthreads();
  if (t==0){
    float4 r = wred4[0];
    #pragma unroll
    for (int i=1;i<8;++i){
      float4 b = wred4[i];
      r.x = fminf(r.x,b.x); r.y = fmaxf(r.y,b.y); r.z += b.z; r.w += b.w;
    }
    float mean = r.z * (1.f/NG);
    float var  = fmaxf(r.w*(1.f/NG) - mean*mean, 0.f);
    float sd   = sqrtf(var) + (1e-8f/3.f);
    float h    = 1.06f * sd * N_POW_M02;
    float lo = r.x - 1e-6f, hi = r.y + 1e-6f;
    sc[0] = lo;
    sc[1] = (hi-lo)*(1.f/(GRID_PTS-1));
    sc[2] = NEG_HALF_LOG2E/(h*h);
    pmean[blockIdx.x] = mean;
    pmax_[blockIdx.x] = r.y;
  }
  __syncthreads();
  float lo = sc[0], st = sc[1], kk = sc[2];
  float gv = lo + st*(float)t;
  // density at grid point t (sum over 512 samples; scale cancels in cdf norm)
  float acc = 0.f;
  if (t < GRID_PTS){
    const float4* xs4 = (const float4*)xs;
    #pragma unroll 4
    for (int i=0;i<NG/4;++i){
      float4 x4 = xs4[i];
      float a;
      a = gv-x4.x; acc += fexp2(kk*a*a);
      a = gv-x4.y; acc += fexp2(kk*a*a);
      a = gv-x4.z; acc += fexp2(kk*a*a);
      a = gv-x4.w; acc += fexp2(kk*a*a);
    }
  }
  // inclusive scan: wave shuffle-scan + block offset
  float sv = acc;
  #pragma unroll
  for (int off=1; off<64; off<<=1){
    float n = __shfl_up(sv, off, 64);
    if (lane >= off) sv += n;
  }
  if (lane==63) wsum[wave] = sv;
  __syncthreads();
  if (t==0){
    float r2 = 0.f;
    #pragma unroll
    for (int i=0;i<8;++i){ woff[i]=r2; r2+=wsum[i]; }
    woff[8]=r2;   // total == cdf[last] (tail threads contribute 0)
  }
  __syncthreads();
  float invt = 1.f/fmaxf(woff[8], 1e-8f);
  float c = (sv + woff[wave]) * invt;
  // soft quantiles
  for (int q=0;q<QN;++q){
    float w = 0.f;
    if (t < GRID_PTS){
      float dist = fabsf(c - (float)q*(1.f/(QN-1)));
      w = frcp(1.f + fexp2(SIG_K*dist));   // sigmoid(-100*dist); inf-safe
    }
    float gw = gv*w;
    #pragma unroll
    for (int m=32;m>0;m>>=1){
      w  += __shfl_xor(w,  m, 64);
      gw += __shfl_xor(gw, m, 64);
    }
    if (lane==0){ redw[q][wave]=w; redg[q][wave]=gw; }
  }
  __syncthreads();
  if (t < QN){
    float sw=0.f, sgw=0.f;
    #pragma unroll
    for (int i=0;i<8;++i){ sw+=redw[t][i]; sgw+=redg[t][i]; }
    qs[t] = sgw / (sw + 1e-8f);
  }
  __syncthreads();
  // fused projection: this block owns kW rows [d*20, d*20+20)
  if (t < ODIM){
    float a = 0.f;
    const float* kwb = kW + (size_t)d*QN*ODIM + t;
    #pragma unroll
    for (int q=0;q<QN;++q) a += qs[q]*kwb[q*ODIM];
    if (d==0) a += kb[t];
    atomicAdd(&kacc[g*ODIM + t], a);
  }
}

// ---------------- pooled linear head ----------------
// grid = GNUM, 128 threads: o = t&31, d-group = t>>5
__global__ void k_pool_h(const float* __restrict__ pmean, const float* __restrict__ pmax,
                         const float* __restrict__ pool_w,
                         const float* __restrict__ lpW, const float* __restrict__ lpb,
                         float* macc){
  int g = blockIdx.x;
  int t = threadIdx.x;
  int o = t & 31, dg = t >> 5;
  float pw0 = pool_w[0], pw1 = pool_w[1];
  float acc = 0.f;
  for (int d = dg; d < HC; d += 4){
    float wp = pw0*pmean[g*HC+d] + pw1*pmax[g*HC+d];
    acc += wp * lpW[d*ODIM + o];
  }
  __shared__ float red[128];
  red[t] = acc;
  __syncthreads();
  if (dg < 2) red[t] += red[t+64];
  __syncthreads();
  if (dg == 0)
    macc[g*ODIM + o] = red[t] + red[t+32] + lpb[o];
}

// ============ fused GAT: x@W + attention logits + inits ============
// grid 1024, 256 threads: 2 nodes x 128 cols
__global__ __launch_bounds__(256) void k_xw(const float* __restrict__ cur, int do_relu,
        const float* __restrict__ W, const float* __restrict__ as_, const float* __restrict__ ad_,
        const float* __restrict__ bias,
        float* __restrict__ xh, float* __restrict__ als, float* __restrict__ ald,
        float* __restrict__ outb, float* __restrict__ emax, float* __restrict__ denom){
  int t = threadIdx.x;
  int ln = t >> 7, j = t & 127;
  int n = blockIdx.x*2 + ln;
  __shared__ float rows[2][HC];
  float v = cur[(size_t)n*HC + j];
  if (do_relu) v = fmaxf(v, 0.f);
  rows[ln][j] = v;
  __syncthreads();
  float acc = 0.f;
  #pragma unroll 8
  for (int c2=0;c2<HC;++c2)
    acc += rows[ln][c2]*W[(size_t)c2*HC + j];
  xh[(size_t)n*HC + j] = acc;
  // per-head attention logit partials (32 channels per head, within half-wave)
  int h = j >> 5, cc = j & 31;
  float ps = acc*as_[h*HID+cc], pd = acc*ad_[h*HID+cc];
  #pragma unroll
  for (int m=16;m>0;m>>=1){
    ps += __shfl_xor(ps, m, 32);
    pd += __shfl_xor(pd, m, 32);
  }
  if (cc==0){ als[n*HEADS+h]=ps; ald[n*HEADS+h]=pd; }
  // init next-layer buffers (sequential stream: prior agg already consumed them)
  int gid = blockIdx.x*256 + t;
  outb[gid] = bias[gid & 127];
  if (gid < NN*HEADS){ emax[gid] = -INFINITY; denom[gid]=0.f; }
}

__device__ __forceinline__ void atomicMaxF(float* a, float v){
  if (v >= 0.f) atomicMax((int*)a, __float_as_int(v));
  else          atomicMin((unsigned int*)a, __float_as_uint(v));
}

__global__ void k_emax(const int* __restrict__ src, const int* __restrict__ dst,
                       const float* __restrict__ als, const float* __restrict__ ald,
                       float* __restrict__ emax){
  int eid = blockIdx.x*blockDim.x + threadIdx.x;
  if (eid >= NE) return;
  int s = (eid < EE) ? src[eid] : (eid - EE);
  int d = (eid < EE) ? dst[eid] : (eid - EE);
  #pragma unroll
  for (int h=0; h<HEADS; ++h){
    float e = als[s*4+h] + ald[d*4+h];
    e = (e >= 0.f) ? e : 0.2f*e;
    atomicMaxF(&emax[d*4+h], e);
  }
}

__global__ void k_eexp(const int* __restrict__ src, const int* __restrict__ dst,
                       const float* __restrict__ als, const float* __restrict__ ald,
                       const float* __restrict__ emax, float* __restrict__ eexp,
                       float* __restrict__ denom){
  int eid = blockIdx.x*blockDim.x + threadIdx.x;
  if (eid >= NE) return;
  int s = (eid < EE) ? src[eid] : (eid - EE);
  int d = (eid < EE) ? dst[eid] : (eid - EE);
  #pragma unroll
  for (int h=0; h<HEADS; ++h){
    float e = als[s*4+h] + ald[d*4+h];
    e = (e >= 0.f) ? e : 0.2f*e;
    float v = fexp2(LOG2E*(e - emax[d*4+h]));
    eexp[eid*4+h] = v;
    atomicAdd(&denom[d*4+h], v);
  }
}

// per (edge, channel) atomic aggregation
__global__ void k_agg(const int* __restrict__ src, const int* __restrict__ dst,
                      const float* __restrict__ eexp, const float* __restrict__ denom,
                      const float* __restrict__ xh, float* __restrict__ out){
  long long gid = (long long)blockIdx.x*blockDim.x + threadIdx.x;
  if (gid >= (long long)NE*HC) return;
  int eid = (int)(gid >> 7);
  int c   = (int)(gid & 127);
  int h   = c >> 5;
  int s = (eid < EE) ? src[eid] : (eid - EE);
  int d = (eid < EE) ? dst[eid] : (eid - EE);
  float alpha = eexp[eid*4+h] / (denom[d*4+h] + 1e-16f);
  atomicAdd(&out[(size_t)d*HC + c], alpha * xh[(size_t)s*HC + c]);
}

// ---------------- final risk ----------------
__global__ void k_final(const float* __restrict__ macc, const float* __restrict__ kacc,
                        const float* __restrict__ beta, const float* __restrict__ h0,
                        float* __restrict__ out){
  int t = threadIdx.x;   // 128
  int g = t >> 5, o = t & 31;
  __shared__ float sdm[128];
  float s3 = macc[t] + macc[t+128] + macc[t+256]
           + kacc[t] + kacc[t+128] + kacc[t+256];
  sdm[t] = s3 * (1.f/3.f) * beta[o];
  __syncthreads();
  if ((t & 31) == 0){
    float s = 0.f;
    #pragma unroll
    for (int i=0;i<32;++i) s += sdm[g*32+i];
    out[g] = s + h0[0];
  }
}

extern "C" void kernel_launch(void* const* d_in, const int* in_sizes, int n_in,
                              void* d_out, int out_size, void* d_ws, size_t ws_size,
                              hipStream_t stream) {
  (void)in_sizes; (void)n_in; (void)out_size; (void)ws_size;
  const float* x    = (const float*)d_in[0];
  const int*   ei   = (const int*)d_in[1];
  const int*   srcp = ei;
  const int*   dstp = ei + EE;
  const float* W[2]   = {(const float*)d_in[3], (const float*)d_in[7]};
  const float* As[2]  = {(const float*)d_in[4], (const float*)d_in[8]};
  const float* Ad[2]  = {(const float*)d_in[5], (const float*)d_in[9]};
  const float* Bi[2]  = {(const float*)d_in[6], (const float*)d_in[10]};
  const float* lpW[3] = {(const float*)d_in[11], (const float*)d_in[13], (const float*)d_in[15]};
  const float* lpb[3] = {(const float*)d_in[12], (const float*)d_in[14], (const float*)d_in[16]};
  const float* kW[3]  = {(const float*)d_in[17], (const float*)d_in[19], (const float*)d_in[21]};
  const float* kb[3]  = {(const float*)d_in[18], (const float*)d_in[20], (const float*)d_in[22]};
  const float* poolw  = (const float*)d_in[23];
  const float* beta   = (const float*)d_in[24];
  const float* h0     = (const float*)d_in[25];
  float* out = (float*)d_out;

  // workspace layout (floats)
  float* ws = (float*)d_ws;
  float* cur1   = ws;                 // 262144
  float* cur2   = cur1 + 262144;      // 262144
  float* xh     = cur2 + 262144;      // 262144
  float* als    = xh + 262144;        // 8192
  float* ald    = als + 8192;         // 8192
  float* emax   = ald + 8192;         // 8192
  float* denom  = emax + 8192;        // 8192
  float* eexp   = denom + 8192;       // 139264
  float* pmean  = eexp + 139264;      // 512
  float* pmax   = pmean + 512;        // 512
  float* macc   = pmax + 512;         // 384 (3 slots x 128)
  float* kacc   = macc + 384;         // 384 (3 slots x 128)

  auto readout = [&](const float* cur, int relu, int i){
    k_kde    <<<512, 512, 0, stream>>>(cur, relu, kW[i], kb[i], kacc + i*128, pmean, pmax);
    k_pool_h <<<GNUM, 128, 0, stream>>>(pmean, pmax, poolw, lpW[i], lpb[i], macc + i*128);
  };
  auto gat = [&](const float* in, int relu, float* o, int l){
    k_xw   <<<1024, 256, 0, stream>>>(in, relu, W[l], As[l], Ad[l], Bi[l],
                                      xh, als, ald, o, emax, denom);
    k_emax <<<(NE+255)/256, 256, 0, stream>>>(srcp, dstp, als, ald, emax);
    k_eexp <<<(NE+255)/256, 256, 0, stream>>>(srcp, dstp, als, ald, emax, eexp, denom);
    k_agg  <<<(int)(((long long)NE*HC+255)/256), 256, 0, stream>>>(srcp, dstp, eexp, denom, xh, o);
  };

  k_init_acc<<<1, 384, 0, stream>>>(kacc);
  readout(x, 0, 0);
  gat(x, 0, cur1, 0);
  readout(cur1, 1, 1);     // relu fused into loads
  gat(cur1, 1, cur2, 1);
  readout(cur2, 0, 2);
  k_final<<<1, 128, 0, stream>>>(macc, kacc, beta, h0, out);
}

// Round 4
// 260.866 us; speedup vs baseline: 2.0858x; 1.2381x over previous
//
#include <hip/hip_runtime.h>
#include <math.h>

// ---- static config (mirror of reference) ----
#define GNUM 4
#define NG 512
#define NN 2048
#define EE 32768
#define HC 128
#define HEADS 4
#define HID 32
#define GRID_PTS 500
#define QN 20
#define ODIM 32
#define MAXE 160              // per-dst edge cap (deg ~ Poisson(16); P(>150) ~ 0)

#define LOG2E 1.44269504088896340736f
#define NEG_HALF_LOG2E -0.72134752044448170368f
#define N_POW_M02 0.2871745887492588f   // 512^-0.2
#define SIG_K 144.269504089f            // 100 * log2(e)

__device__ __forceinline__ float fexp2(float x){ return __builtin_amdgcn_exp2f(x); }
__device__ __forceinline__ float frcp(float x){ return __builtin_amdgcn_rcpf(x); }

// ============ CSR build (once) + zero accumulators ============
// single block, 1024 threads
__global__ __launch_bounds__(1024) void k_csr(const int* __restrict__ src,
        const int* __restrict__ dst, int* __restrict__ csr_src,
        int* __restrict__ csr_off, float* __restrict__ accz){
  __shared__ int cnt[NN];          // 8 KB
  __shared__ int woffs[16];
  int t = threadIdx.x, lane = t & 63, wid = t >> 6;
  cnt[t] = 0; cnt[t+1024] = 0;
  if (t < 768) accz[t] = 0.f;      // macc[384] + kacc[384]
  __syncthreads();
  for (int e=t; e<EE; e+=1024) atomicAdd(&cnt[dst[e]], 1);
  __syncthreads();
  // exclusive scan over 2048 (pairs per thread + wave scan + wave offsets)
  int a0 = cnt[2*t], a1 = cnt[2*t+1];
  int s = a0 + a1;
  #pragma unroll
  for (int off=1; off<64; off<<=1){
    int n = __shfl_up(s, off, 64);
    if (lane >= off) s += n;
  }
  if (lane==63) woffs[wid] = s;
  __syncthreads();
  if (t==0){
    int run=0;
    #pragma unroll
    for (int i=0;i<16;++i){ int tmp=woffs[i]; woffs[i]=run; run+=tmp; }
  }
  __syncthreads();
  int e0 = s + woffs[wid] - a0 - a1;     // exclusive offset of element 2t
  csr_off[2*t] = e0;
  csr_off[2*t+1] = e0 + a0;
  if (t==0) csr_off[NN] = EE;
  __syncthreads();
  cnt[2*t] = e0; cnt[2*t+1] = e0 + a0;   // reuse as running positions
  __syncthreads();
  for (int e=t; e<EE; e+=1024){
    int dd = dst[e];
    int p = atomicAdd(&cnt[dd], 1);
    csr_src[p] = src[e];
  }
}

// ============ fused KDE readout: stats + density + cdf + quantiles + proj + pooled-linear ============
// block = (g*128+d), 512 threads
__global__ __launch_bounds__(512) void k_kde(const float* __restrict__ cur, int do_relu,
        const float* __restrict__ kW, const float* __restrict__ kb,
        float* __restrict__ kacc,
        const float* __restrict__ lpW, const float* __restrict__ lpb,
        const float* __restrict__ poolw, float* __restrict__ macc){
  int g = blockIdx.x >> 7, d = blockIdx.x & 127;
  int t = threadIdx.x;
  int lane = t & 63, wave = t >> 6;
  __shared__ __align__(16) float2 xs[NG];   // (x, x^2)
  __shared__ float4 wred4[8];
  __shared__ float sc[4];
  __shared__ float wsum[8], woff[9];
  __shared__ float redw[QN][8], redg[QN][8];
  __shared__ float qs[QN];

  float v = cur[((size_t)g*NG + t)*HC + d];
  if (do_relu) v = fmaxf(v, 0.f);
  xs[t] = make_float2(v, v*v);
  // wave-level min/max/sum/sumsq
  float mn=v, mx=v, sm=v, sq=v*v;
  #pragma unroll
  for (int m=32; m>0; m>>=1){
    mn = fminf(mn, __shfl_xor(mn, m, 64));
    mx = fmaxf(mx, __shfl_xor(mx, m, 64));
    sm += __shfl_xor(sm, m, 64);
    sq += __shfl_xor(sq, m, 64);
  }
  if (lane==0) wred4[wave] = make_float4(mn,mx,sm,sq);
  __syncthreads();
  if (t==0){
    float4 r = wred4[0];
    #pragma unroll
    for (int i=1;i<8;++i){
      float4 b = wred4[i];
      r.x = fminf(r.x,b.x); r.y = fmaxf(r.y,b.y); r.z += b.z; r.w += b.w;
    }
    float mean = r.z * (1.f/NG);
    float var  = fmaxf(r.w*(1.f/NG) - mean*mean, 0.f);
    float sd   = sqrtf(var) + (1e-8f/3.f);
    float h    = 1.06f * sd * N_POW_M02;
    float lo = r.x - 1e-6f, hi = r.y + 1e-6f;
    sc[0] = lo;
    sc[1] = (hi-lo)*(1.f/(GRID_PTS-1));
    sc[2] = NEG_HALF_LOG2E/(h*h);
    sc[3] = poolw[0]*mean + poolw[1]*r.y;   // weighted pooled value
  }
  __syncthreads();
  float lo = sc[0], st = sc[1], kk = sc[2];
  float gv = lo + st*(float)t;
  // density at grid point t: exp2(kk*gv^2 + (-2kk*gv)*x + kk*x^2), 2 fma + exp
  float acc = 0.f;
  if (t < GRID_PTS){
    float c0 = kk*gv*gv, c1 = -2.f*kk*gv;
    const float4* p4 = (const float4*)xs;
    #pragma unroll 4
    for (int i=0;i<NG/2;++i){
      float4 s2 = p4[i];
      acc += fexp2(fmaf(kk, s2.y, fmaf(c1, s2.x, c0)));
      acc += fexp2(fmaf(kk, s2.w, fmaf(c1, s2.z, c0)));
    }
  }
  // inclusive scan: wave shuffle-scan + block offset
  float sv = acc;
  #pragma unroll
  for (int off=1; off<64; off<<=1){
    float n = __shfl_up(sv, off, 64);
    if (lane >= off) sv += n;
  }
  if (lane==63) wsum[wave] = sv;
  __syncthreads();
  if (t==0){
    float r2 = 0.f;
    #pragma unroll
    for (int i=0;i<8;++i){ woff[i]=r2; r2+=wsum[i]; }
    woff[8]=r2;
  }
  if (t < QN*8){ ((float*)redw)[t]=0.f; ((float*)redg)[t]=0.f; }
  __syncthreads();
  float invt = 1.f/fmaxf(woff[8], 1e-8f);
  float c = (sv + woff[wave]) * invt;      // cdf (monotone across lanes; tail lanes -> 1)
  // wave-uniform quantile window: sigmoid(-100*dist) < ~1e-7 outside +-0.16
  float cw0 = __shfl(c, 0, 64), cw1 = __shfl(c, 63, 64);
  int qlo = max(0, (int)ceilf((cw0 - 0.17f)*(float)(QN-1)));
  int qhi = min(QN-1, (int)floorf((cw1 + 0.17f)*(float)(QN-1)));
  for (int q=qlo; q<=qhi; ++q){
    float w = 0.f;
    if (t < GRID_PTS){
      float dist = fabsf(c - (float)q*(1.f/(QN-1)));
      w = frcp(1.f + fexp2(SIG_K*dist));   // sigmoid(-100*dist)
    }
    float gw = gv*w;
    #pragma unroll
    for (int m=32;m>0;m>>=1){
      w  += __shfl_xor(w,  m, 64);
      gw += __shfl_xor(gw, m, 64);
    }
    if (lane==0){ redw[q][wave]=w; redg[q][wave]=gw; }
  }
  __syncthreads();
  if (t < QN){
    float sw=0.f, sgw=0.f;
    #pragma unroll
    for (int i=0;i<8;++i){ sw+=redw[t][i]; sgw+=redg[t][i]; }
    qs[t] = sgw / (sw + 1e-8f);
  }
  __syncthreads();
  if (t < ODIM){
    // KDE projection: this block owns kW rows [d*20, d*20+20)
    float a = 0.f;
    const float* kwb = kW + (size_t)d*QN*ODIM + t;
    #pragma unroll
    for (int q=0;q<QN;++q) a += qs[q]*kwb[q*ODIM];
    if (d==0) a += kb[t];
    atomicAdd(&kacc[g*ODIM + t], a);
    // pooled linear head: wp * lpW[d,:]
    float b = sc[3]*lpW[d*ODIM + t];
    if (d==0) b += lpb[t];
    atomicAdd(&macc[g*ODIM + t], b);
  }
}

// ============ fused GAT: x@W + attention logits ============
// grid 1024, 256 threads: 2 nodes x 128 cols
__global__ __launch_bounds__(256) void k_xw(const float* __restrict__ cur, int do_relu,
        const float* __restrict__ W, const float* __restrict__ as_, const float* __restrict__ ad_,
        float* __restrict__ xh, float* __restrict__ als, float* __restrict__ ald){
  int t = threadIdx.x;
  int ln = t >> 7, j = t & 127;
  int n = blockIdx.x*2 + ln;
  __shared__ float rows[2][HC];
  float v = cur[(size_t)n*HC + j];
  if (do_relu) v = fmaxf(v, 0.f);
  rows[ln][j] = v;
  __syncthreads();
  float acc = 0.f;
  #pragma unroll 8
  for (int c2=0;c2<HC;++c2)
    acc += rows[ln][c2]*W[(size_t)c2*HC + j];
  xh[(size_t)n*HC + j] = acc;
  // per-head attention logit partials (32 channels per head)
  int h = j >> 5, cc = j & 31;
  float ps = acc*as_[h*HID+cc], pd = acc*ad_[h*HID+cc];
  #pragma unroll
  for (int m=16;m>0;m>>=1){
    ps += __shfl_xor(ps, m, 32);
    pd += __shfl_xor(pd, m, 32);
  }
  if (cc==0){ als[n*HEADS+h]=ps; ald[n*HEADS+h]=pd; }
}

// ============ GAT gather: softmax + aggregate per dst, no atomics ============
// block per dst node, 128 threads (one per channel)
__global__ __launch_bounds__(128) void k_gather(const int* __restrict__ csr_src,
        const int* __restrict__ csr_off,
        const float* __restrict__ als, const float* __restrict__ ald,
        const float* __restrict__ xh, const float* __restrict__ bias,
        float* __restrict__ out){
  int d = blockIdx.x, t = threadIdx.x;
  int beg = csr_off[d];
  int deg = csr_off[d+1] - beg;
  int E = min(deg + 1, MAXE);          // + self loop
  __shared__ int ssrc[MAXE];
  __shared__ float sexp[MAXE][HEADS];
  __shared__ float smax[HEADS], sfac[HEADS];
  float a0 = ald[d*4+0], a1 = ald[d*4+1], a2 = ald[d*4+2], a3 = ald[d*4+3];
  for (int i=t; i<E; i+=128){
    int s = (i < deg) ? csr_src[beg+i] : d;
    ssrc[i] = s;
    float e0 = als[s*4+0]+a0, e1 = als[s*4+1]+a1, e2 = als[s*4+2]+a2, e3 = als[s*4+3]+a3;
    e0 = (e0>=0.f)? e0 : 0.2f*e0;
    e1 = (e1>=0.f)? e1 : 0.2f*e1;
    e2 = (e2>=0.f)? e2 : 0.2f*e2;
    e3 = (e3>=0.f)? e3 : 0.2f*e3;
    sexp[i][0]=e0; sexp[i][1]=e1; sexp[i][2]=e2; sexp[i][3]=e3;
  }
  __syncthreads();
  if (t < HEADS){
    float m = -INFINITY;
    for (int i=0;i<E;++i) m = fmaxf(m, sexp[i][t]);
    smax[t] = m;
  }
  __syncthreads();
  for (int i=t; i<E; i+=128){
    #pragma unroll
    for (int h=0;h<HEADS;++h)
      sexp[i][h] = fexp2(LOG2E*(sexp[i][h]-smax[h]));
  }
  __syncthreads();
  if (t < HEADS){
    float sdn = 0.f;
    for (int i=0;i<E;++i) sdn += sexp[i][t];
    sfac[t] = 1.f/(sdn + 1e-16f);
  }
  __syncthreads();
  int h = t >> 5;
  float fac = sfac[h];
  float acc = bias[t];
  for (int i=0;i<E;++i)
    acc += sexp[i][h]*fac * xh[(size_t)ssrc[i]*HC + t];
  out[(size_t)d*HC + t] = acc;
}

// ---------------- final risk ----------------
__global__ void k_final(const float* __restrict__ macc, const float* __restrict__ kacc,
                        const float* __restrict__ beta, const float* __restrict__ h0,
                        float* __restrict__ out){
  int t = threadIdx.x;   // 128
  int g = t >> 5, o = t & 31;
  __shared__ float sdm[128];
  float s3 = macc[t] + macc[t+128] + macc[t+256]
           + kacc[t] + kacc[t+128] + kacc[t+256];
  sdm[t] = s3 * (1.f/3.f) * beta[o];
  __syncthreads();
  if ((t & 31) == 0){
    float s = 0.f;
    #pragma unroll
    for (int i=0;i<32;++i) s += sdm[g*32+i];
    out[g] = s + h0[0];
  }
}

extern "C" void kernel_launch(void* const* d_in, const int* in_sizes, int n_in,
                              void* d_out, int out_size, void* d_ws, size_t ws_size,
                              hipStream_t stream) {
  (void)in_sizes; (void)n_in; (void)out_size; (void)ws_size;
  const float* x    = (const float*)d_in[0];
  const int*   ei   = (const int*)d_in[1];
  const int*   srcp = ei;
  const int*   dstp = ei + EE;
  const float* W[2]   = {(const float*)d_in[3], (const float*)d_in[7]};
  const float* As[2]  = {(const float*)d_in[4], (const float*)d_in[8]};
  const float* Ad[2]  = {(const float*)d_in[5], (const float*)d_in[9]};
  const float* Bi[2]  = {(const float*)d_in[6], (const float*)d_in[10]};
  const float* lpW[3] = {(const float*)d_in[11], (const float*)d_in[13], (const float*)d_in[15]};
  const float* lpb[3] = {(const float*)d_in[12], (const float*)d_in[14], (const float*)d_in[16]};
  const float* kW[3]  = {(const float*)d_in[17], (const float*)d_in[19], (const float*)d_in[21]};
  const float* kb[3]  = {(const float*)d_in[18], (const float*)d_in[20], (const float*)d_in[22]};
  const float* poolw  = (const float*)d_in[23];
  const float* beta   = (const float*)d_in[24];
  const float* h0     = (const float*)d_in[25];
  float* out = (float*)d_out;

  // workspace layout
  float* ws = (float*)d_ws;
  float* cur1   = ws;                 // 262144
  float* cur2   = cur1 + 262144;      // 262144
  float* xh     = cur2 + 262144;      // 262144
  float* als    = xh + 262144;        // 8192
  float* ald    = als + 8192;         // 8192
  float* macc   = ald + 8192;         // 384 (3 slots x 128)
  float* kacc   = macc + 384;         // 384
  int*   csr_off = (int*)(kacc + 384);   // 2049
  int*   csr_src = csr_off + 2049;       // 32768

  k_csr<<<1, 1024, 0, stream>>>(srcp, dstp, csr_src, csr_off, macc);

  // readout 0 (input x) + GAT layer 0
  k_kde   <<<512, 512, 0, stream>>>(x, 0, kW[0], kb[0], kacc, lpW[0], lpb[0], poolw, macc);
  k_xw    <<<1024, 256, 0, stream>>>(x, 0, W[0], As[0], Ad[0], xh, als, ald);
  k_gather<<<NN, 128, 0, stream>>>(csr_src, csr_off, als, ald, xh, Bi[0], cur1);

  // readout 1 (relu(cur1) fused) + GAT layer 1 (relu fused into loads)
  k_kde   <<<512, 512, 0, stream>>>(cur1, 1, kW[1], kb[1], kacc+128, lpW[1], lpb[1], poolw, macc+128);
  k_xw    <<<1024, 256, 0, stream>>>(cur1, 1, W[1], As[1], Ad[1], xh, als, ald);
  k_gather<<<NN, 128, 0, stream>>>(csr_src, csr_off, als, ald, xh, Bi[1], cur2);

  // readout 2
  k_kde   <<<512, 512, 0, stream>>>(cur2, 0, kW[2], kb[2], kacc+256, lpW[2], lpb[2], poolw, macc+256);

  k_final<<<1, 128, 0, stream>>>(macc, kacc, beta, h0, out);
}

// Round 5
// 210.966 us; speedup vs baseline: 2.5791x; 1.2365x over previous
//
#include <hip/hip_runtime.h>
#include <math.h>

// ---- static config (mirror of reference) ----
#define GNUM 4
#define NG 512
#define NN 2048
#define EE 32768
#define HC 128
#define HEADS 4
#define HID 32
#define GRID_PTS 500
#define QN 20
#define ODIM 32
#define MAXE 160              // per-dst edge cap (deg ~ Poisson(16); P(>159) ~ 0)

#define LOG2E 1.44269504088896340736f
#define NEG_HALF_LOG2E -0.72134752044448170368f
#define N_POW_M02 0.2871745887492588f   // 512^-0.2
#define SIG_K 144.269504089f            // 100 * log2(e)

__device__ __forceinline__ float fexp2(float x){ return __builtin_amdgcn_exp2f(x); }
__device__ __forceinline__ float frcp(float x){ return __builtin_amdgcn_rcpf(x); }

// ============ zero: pos[2048] + macc/kacc[768] ============
__global__ __launch_bounds__(1024) void k_zero(int* __restrict__ pos, float* __restrict__ acc){
  int t = threadIdx.x;
  pos[t] = 0; pos[t+1024] = 0;
  if (t < 768) acc[t] = 0.f;
}

// ============ fused layer kernel ============
// blocks [0,512): KDE readout (stats+density+cdf+quantiles+proj+pooled-linear), 512 thr
// blocks [512,512+nxw): x@W + attention logits, 4 nodes/block; layer 0 also scatters CSR
__global__ __launch_bounds__(512) void k_layer(const float* __restrict__ cur, int do_relu,
        // kde
        const float* __restrict__ kW, const float* __restrict__ kb, float* __restrict__ kacc,
        const float* __restrict__ lpW, const float* __restrict__ lpb,
        const float* __restrict__ poolw, float* __restrict__ macc,
        // xw
        const float* __restrict__ W, const float* __restrict__ as_, const float* __restrict__ ad_,
        float* __restrict__ xh, float* __restrict__ als, float* __restrict__ ald,
        // edge fill (layer 0 only)
        int do_fill, const int* __restrict__ src, const int* __restrict__ dst,
        int* __restrict__ pos, int* __restrict__ csr_src){
  int t = threadIdx.x;
  if (blockIdx.x < 512){
    // ---------------- KDE path ----------------
    int g = blockIdx.x >> 7, d = blockIdx.x & 127;
    int lane = t & 63, wave = t >> 6;
    __shared__ __align__(16) float2 xs[NG];   // (x, x^2)
    __shared__ float4 wred4[8];
    __shared__ float sc[4];
    __shared__ float wsum[8], woff[9];
    __shared__ float redw[QN][8], redg[QN][8];
    __shared__ float qs[QN];

    float v = cur[((size_t)g*NG + t)*HC + d];
    if (do_relu) v = fmaxf(v, 0.f);
    xs[t] = make_float2(v, v*v);
    float mn=v, mx=v, sm=v, sq=v*v;
    #pragma unroll
    for (int m=32; m>0; m>>=1){
      mn = fminf(mn, __shfl_xor(mn, m, 64));
      mx = fmaxf(mx, __shfl_xor(mx, m, 64));
      sm += __shfl_xor(sm, m, 64);
      sq += __shfl_xor(sq, m, 64);
    }
    if (lane==0) wred4[wave] = make_float4(mn,mx,sm,sq);
    __syncthreads();
    if (t==0){
      float4 r = wred4[0];
      #pragma unroll
      for (int i=1;i<8;++i){
        float4 b = wred4[i];
        r.x = fminf(r.x,b.x); r.y = fmaxf(r.y,b.y); r.z += b.z; r.w += b.w;
      }
      float mean = r.z * (1.f/NG);
      float var  = fmaxf(r.w*(1.f/NG) - mean*mean, 0.f);
      float sd   = sqrtf(var) + (1e-8f/3.f);
      float h    = 1.06f * sd * N_POW_M02;
      float lo = r.x - 1e-6f, hi = r.y + 1e-6f;
      sc[0] = lo;
      sc[1] = (hi-lo)*(1.f/(GRID_PTS-1));
      sc[2] = NEG_HALF_LOG2E/(h*h);
      sc[3] = poolw[0]*mean + poolw[1]*r.y;
    }
    __syncthreads();
    float lo = sc[0], st = sc[1], kk = sc[2];
    float gv = lo + st*(float)t;
    // density: exp2(kk*x^2 + c1*x + c0), 2 fma + exp per sample
    float acc = 0.f;
    if (t < GRID_PTS){
      float c0 = kk*gv*gv, c1 = -2.f*kk*gv;
      const float4* p4 = (const float4*)xs;
      #pragma unroll 4
      for (int i=0;i<NG/2;++i){
        float4 s2 = p4[i];
        acc += fexp2(fmaf(kk, s2.y, fmaf(c1, s2.x, c0)));
        acc += fexp2(fmaf(kk, s2.w, fmaf(c1, s2.z, c0)));
      }
    }
    // inclusive scan
    float sv = acc;
    #pragma unroll
    for (int off=1; off<64; off<<=1){
      float n = __shfl_up(sv, off, 64);
      if (lane >= off) sv += n;
    }
    if (lane==63) wsum[wave] = sv;
    __syncthreads();
    if (t==0){
      float r2 = 0.f;
      #pragma unroll
      for (int i=0;i<8;++i){ woff[i]=r2; r2+=wsum[i]; }
      woff[8]=r2;
    }
    if (t < QN*8){ ((float*)redw)[t]=0.f; ((float*)redg)[t]=0.f; }
    __syncthreads();
    float invt = 1.f/fmaxf(woff[8], 1e-8f);
    float c = (sv + woff[wave]) * invt;
    // wave-uniform quantile window (sigmoid < ~1e-7 outside +-0.17)
    float cw0 = __shfl(c, 0, 64), cw1 = __shfl(c, 63, 64);
    int qlo = max(0, (int)ceilf((cw0 - 0.17f)*(float)(QN-1)));
    int qhi = min(QN-1, (int)floorf((cw1 + 0.17f)*(float)(QN-1)));
    for (int q=qlo; q<=qhi; ++q){
      float w = 0.f;
      if (t < GRID_PTS){
        float dist = fabsf(c - (float)q*(1.f/(QN-1)));
        w = frcp(1.f + fexp2(SIG_K*dist));
      }
      float gw = gv*w;
      #pragma unroll
      for (int m=32;m>0;m>>=1){
        w  += __shfl_xor(w,  m, 64);
        gw += __shfl_xor(gw, m, 64);
      }
      if (lane==0){ redw[q][wave]=w; redg[q][wave]=gw; }
    }
    __syncthreads();
    if (t < QN){
      float sw=0.f, sgw=0.f;
      #pragma unroll
      for (int i=0;i<8;++i){ sw+=redw[t][i]; sgw+=redg[t][i]; }
      qs[t] = sgw / (sw + 1e-8f);
    }
    __syncthreads();
    if (t < ODIM){
      float a = 0.f;
      const float* kwb = kW + (size_t)d*QN*ODIM + t;
      #pragma unroll
      for (int q=0;q<QN;++q) a += qs[q]*kwb[q*ODIM];
      if (d==0) a += kb[t];
      atomicAdd(&kacc[g*ODIM + t], a);
      float b = sc[3]*lpW[d*ODIM + t];
      if (d==0) b += lpb[t];
      atomicAdd(&macc[g*ODIM + t], b);
    }
  } else {
    // ---------------- x@W path: 4 nodes/block ----------------
    int b2 = blockIdx.x - 512;
    if (do_fill){
      int e = b2*512 + t;
      if (e < EE){
        int dd = dst[e];
        int p = atomicAdd(&pos[dd], 1);
        if (p < MAXE) csr_src[dd*MAXE + p] = src[e];
      }
    }
    int ln = t >> 7, j = t & 127;
    int n = b2*4 + ln;
    __shared__ float rows[4][HC];
    float v = cur[(size_t)n*HC + j];
    if (do_relu) v = fmaxf(v, 0.f);
    rows[ln][j] = v;
    __syncthreads();
    float acc = 0.f;
    #pragma unroll 8
    for (int c2=0;c2<HC;++c2)
      acc += rows[ln][c2]*W[(size_t)c2*HC + j];
    xh[(size_t)n*HC + j] = acc;
    int h = j >> 5, cc = j & 31;
    float ps = acc*as_[h*HID+cc], pd = acc*ad_[h*HID+cc];
    #pragma unroll
    for (int m=16;m>0;m>>=1){
      ps += __shfl_xor(ps, m, 32);
      pd += __shfl_xor(pd, m, 32);
    }
    if (cc==0){ als[n*HEADS+h]=ps; ald[n*HEADS+h]=pd; }
  }
}

// ============ GAT gather: softmax + aggregate per dst, no atomics ============
// block per dst node, 128 threads (one per channel)
__global__ __launch_bounds__(128) void k_gather(const int* __restrict__ csr_src,
        const int* __restrict__ pos,
        const float* __restrict__ als, const float* __restrict__ ald,
        const float* __restrict__ xh, const float* __restrict__ bias,
        float* __restrict__ out){
  int d = blockIdx.x, t = threadIdx.x;
  int deg = min(pos[d], MAXE-1);
  int E = deg + 1;                     // + self loop
  const int* base = csr_src + d*MAXE;
  __shared__ int ssrc[MAXE];
  __shared__ float sexp[MAXE][HEADS];
  __shared__ float smax[HEADS], sfac[HEADS];
  float a0 = ald[d*4+0], a1 = ald[d*4+1], a2 = ald[d*4+2], a3 = ald[d*4+3];
  for (int i=t; i<E; i+=128){
    int s = (i < deg) ? base[i] : d;
    ssrc[i] = s;
    float e0 = als[s*4+0]+a0, e1 = als[s*4+1]+a1, e2 = als[s*4+2]+a2, e3 = als[s*4+3]+a3;
    e0 = (e0>=0.f)? e0 : 0.2f*e0;
    e1 = (e1>=0.f)? e1 : 0.2f*e1;
    e2 = (e2>=0.f)? e2 : 0.2f*e2;
    e3 = (e3>=0.f)? e3 : 0.2f*e3;
    sexp[i][0]=e0; sexp[i][1]=e1; sexp[i][2]=e2; sexp[i][3]=e3;
  }
  __syncthreads();
  if (t < HEADS){
    float m = -INFINITY;
    for (int i=0;i<E;++i) m = fmaxf(m, sexp[i][t]);
    smax[t] = m;
  }
  __syncthreads();
  for (int i=t; i<E; i+=128){
    #pragma unroll
    for (int h=0;h<HEADS;++h)
      sexp[i][h] = fexp2(LOG2E*(sexp[i][h]-smax[h]));
  }
  __syncthreads();
  if (t < HEADS){
    float sdn = 0.f;
    for (int i=0;i<E;++i) sdn += sexp[i][t];
    sfac[t] = 1.f/(sdn + 1e-16f);
  }
  __syncthreads();
  int h = t >> 5;
  float fac = sfac[h];
  float acc = bias[t];
  for (int i=0;i<E;++i)
    acc += sexp[i][h]*fac * xh[(size_t)ssrc[i]*HC + t];
  out[(size_t)d*HC + t] = acc;
}

// ---------------- final risk ----------------
__global__ void k_final(const float* __restrict__ macc, const float* __restrict__ kacc,
                        const float* __restrict__ beta, const float* __restrict__ h0,
                        float* __restrict__ out){
  int t = threadIdx.x;   // 128
  int g = t >> 5, o = t & 31;
  __shared__ float sdm[128];
  float s3 = macc[t] + macc[t+128] + macc[t+256]
           + kacc[t] + kacc[t+128] + kacc[t+256];
  sdm[t] = s3 * (1.f/3.f) * beta[o];
  __syncthreads();
  if ((t & 31) == 0){
    float s = 0.f;
    #pragma unroll
    for (int i=0;i<32;++i) s += sdm[g*32+i];
    out[g] = s + h0[0];
  }
}

extern "C" void kernel_launch(void* const* d_in, const int* in_sizes, int n_in,
                              void* d_out, int out_size, void* d_ws, size_t ws_size,
                              hipStream_t stream) {
  (void)in_sizes; (void)n_in; (void)out_size; (void)ws_size;
  const float* x    = (const float*)d_in[0];
  const int*   ei   = (const int*)d_in[1];
  const int*   srcp = ei;
  const int*   dstp = ei + EE;
  const float* W[2]   = {(const float*)d_in[3], (const float*)d_in[7]};
  const float* As[2]  = {(const float*)d_in[4], (const float*)d_in[8]};
  const float* Ad[2]  = {(const float*)d_in[5], (const float*)d_in[9]};
  const float* Bi[2]  = {(const float*)d_in[6], (const float*)d_in[10]};
  const float* lpW[3] = {(const float*)d_in[11], (const float*)d_in[13], (const float*)d_in[15]};
  const float* lpb[3] = {(const float*)d_in[12], (const float*)d_in[14], (const float*)d_in[16]};
  const float* kW[3]  = {(const float*)d_in[17], (const float*)d_in[19], (const float*)d_in[21]};
  const float* kb[3]  = {(const float*)d_in[18], (const float*)d_in[20], (const float*)d_in[22]};
  const float* poolw  = (const float*)d_in[23];
  const float* beta   = (const float*)d_in[24];
  const float* h0     = (const float*)d_in[25];
  float* out = (float*)d_out;

  // workspace layout
  float* ws = (float*)d_ws;
  float* cur1   = ws;                 // 262144
  float* cur2   = cur1 + 262144;      // 262144
  float* xh     = cur2 + 262144;      // 262144
  float* als    = xh + 262144;        // 8192
  float* ald    = als + 8192;         // 8192
  float* macc   = ald + 8192;         // 384 (3 slots x 128)  [accz base]
  float* kacc   = macc + 384;         // 384
  int*   pos     = (int*)(kacc + 384);    // 2048
  int*   csr_src = pos + 2048;            // 2048*160

  k_zero<<<1, 1024, 0, stream>>>(pos, macc);

  // layer 0: readout(x) + x@W + CSR fill
  k_layer<<<1024, 512, 0, stream>>>(x, 0, kW[0], kb[0], kacc, lpW[0], lpb[0], poolw, macc,
                                    W[0], As[0], Ad[0], xh, als, ald,
                                    1, srcp, dstp, pos, csr_src);
  k_gather<<<NN, 128, 0, stream>>>(csr_src, pos, als, ald, xh, Bi[0], cur1);

  // layer 1: readout(relu(cur1)) + relu+x@W
  k_layer<<<1024, 512, 0, stream>>>(cur1, 1, kW[1], kb[1], kacc+128, lpW[1], lpb[1], poolw, macc+128,
                                    W[1], As[1], Ad[1], xh, als, ald,
                                    0, srcp, dstp, pos, csr_src);
  k_gather<<<NN, 128, 0, stream>>>(csr_src, pos, als, ald, xh, Bi[1], cur2);

  // readout 2 (kde blocks only)
  k_layer<<<512, 512, 0, stream>>>(cur2, 0, kW[2], kb[2], kacc+256, lpW[2], lpb[2], poolw, macc+256,
                                   nullptr, nullptr, nullptr, nullptr, nullptr, nullptr,
                                   0, nullptr, nullptr, nullptr, nullptr);

  k_final<<<1, 128, 0, stream>>>(macc, kacc, beta, h0, out);
}